// Round 3
// baseline (122.679 us; speedup 1.0000x reference)
//
#include <hip/hip_runtime.h>
#include <cstddef>

#define QK_SCALE 0.17677669529663687f   // 1/sqrt(32)

#define FMA4(acc, sc, c) \
    acc.x = fmaf(sc, c.x, acc.x); acc.y = fmaf(sc, c.y, acc.y); \
    acc.z = fmaf(sc, c.z, acc.z); acc.w = fmaf(sc, c.w, acc.w);

// ---------------- kernel 1: LN(x) + Q/K/V/Gate projections ----------------
// grid 256 x 256; block handles 4 rows; wave w handles matrix w (Wq,Wk,Wv,Wg).
__global__ __launch_bounds__(256) void k1_proj(
    const float* __restrict__ x,
    const float* __restrict__ lng, const float* __restrict__ lnb,
    const float* __restrict__ Wq, const float* __restrict__ Wk,
    const float* __restrict__ Wv, const float* __restrict__ Wg,
    const float* __restrict__ bgv,
    const float* __restrict__ lnbg, const float* __restrict__ lnbb,
    const float* __restrict__ Wb,
    float* __restrict__ qg, float* __restrict__ ktg,
    float* __restrict__ vg, float* __restrict__ gateg,
    float* __restrict__ wbp, float* __restrict__ s12)
{
    __shared__ float xn_s[4][256];
    __shared__ float p1_s[64], p2_s[64];
    const int tid = threadIdx.x;
    const int w = tid >> 6, lane = tid & 63;
    const int gr0 = blockIdx.x * 4;
    const int row = gr0 + w;

    // ---- LayerNorm: one row per wave ----
    float4 xv = *reinterpret_cast<const float4*>(x + row * 256 + lane * 4);
    float s  = xv.x + xv.y + xv.z + xv.w;
    float ss = xv.x*xv.x + xv.y*xv.y + xv.z*xv.z + xv.w*xv.w;
    #pragma unroll
    for (int m = 1; m < 64; m <<= 1) { s += __shfl_xor(s, m); ss += __shfl_xor(ss, m); }
    float mean = s * (1.f/256.f);
    float rstd = rsqrtf(ss*(1.f/256.f) - mean*mean + 1e-5f);
    float4 g4 = *reinterpret_cast<const float4*>(lng + lane*4);
    float4 b4 = *reinterpret_cast<const float4*>(lnb + lane*4);
    float4 xn;
    xn.x = (xv.x-mean)*rstd*g4.x + b4.x;
    xn.y = (xv.y-mean)*rstd*g4.y + b4.y;
    xn.z = (xv.z-mean)*rstd*g4.z + b4.z;
    xn.w = (xv.w-mean)*rstd*g4.w + b4.w;
    *reinterpret_cast<float4*>(&xn_s[w][lane*4]) = xn;
    __syncthreads();

    // ---- wave w computes matrix w for all 4 rows; lane owns 4 output cols ----
    const float* W = (w == 0) ? Wq : (w == 1) ? Wk : (w == 2) ? Wv : Wg;
    const int col = lane << 2;
    float a[4][4];
    #pragma unroll
    for (int r = 0; r < 4; ++r)
        #pragma unroll
        for (int c = 0; c < 4; ++c) a[r][c] = 0.f;

    #pragma unroll 4
    for (int c = 0; c < 256; c += 4) {
        float4 w0 = *reinterpret_cast<const float4*>(W + (size_t)(c+0)*256 + col);
        float4 w1 = *reinterpret_cast<const float4*>(W + (size_t)(c+1)*256 + col);
        float4 w2 = *reinterpret_cast<const float4*>(W + (size_t)(c+2)*256 + col);
        float4 w3 = *reinterpret_cast<const float4*>(W + (size_t)(c+3)*256 + col);
        #pragma unroll
        for (int r = 0; r < 4; ++r) {
            float4 xr = *reinterpret_cast<const float4*>(&xn_s[r][c]);
            a[r][0] = fmaf(xr.x,w0.x, fmaf(xr.y,w1.x, fmaf(xr.z,w2.x, fmaf(xr.w,w3.x, a[r][0]))));
            a[r][1] = fmaf(xr.x,w0.y, fmaf(xr.y,w1.y, fmaf(xr.z,w2.y, fmaf(xr.w,w3.y, a[r][1]))));
            a[r][2] = fmaf(xr.x,w0.z, fmaf(xr.y,w1.z, fmaf(xr.z,w2.z, fmaf(xr.w,w3.z, a[r][2]))));
            a[r][3] = fmaf(xr.x,w0.w, fmaf(xr.y,w1.w, fmaf(xr.z,w2.w, fmaf(xr.w,w3.w, a[r][3]))));
        }
    }

    if (w == 0) {
        #pragma unroll
        for (int r = 0; r < 4; ++r) {
            float4 o; o.x=a[r][0]; o.y=a[r][1]; o.z=a[r][2]; o.w=a[r][3];
            *reinterpret_cast<float4*>(qg + (size_t)(gr0+r)*256 + col) = o;
        }
    } else if (w == 1) {
        #pragma unroll
        for (int r = 0; r < 4; ++r) {
            int gr = gr0 + r, gb = gr >> 9, gl = gr & 511;
            #pragma unroll
            for (int jj = 0; jj < 4; ++jj) {
                int c2 = col + jj;
                ktg[((size_t)(gb*8 + (c2>>5))*32 + (c2&31))*512 + gl] = a[r][jj] * QK_SCALE;
            }
        }
    } else if (w == 2) {
        #pragma unroll
        for (int r = 0; r < 4; ++r) {
            float4 o; o.x=a[r][0]; o.y=a[r][1]; o.z=a[r][2]; o.w=a[r][3];
            *reinterpret_cast<float4*>(vg + (size_t)(gr0+r)*256 + col) = o;
        }
    } else {
        float4 bg4 = *reinterpret_cast<const float4*>(bgv + col);
        #pragma unroll
        for (int r = 0; r < 4; ++r) {
            float4 o;
            o.x = 1.f/(1.f + __expf(-(a[r][0] + bg4.x)));
            o.y = 1.f/(1.f + __expf(-(a[r][1] + bg4.y)));
            o.z = 1.f/(1.f + __expf(-(a[r][2] + bg4.z)));
            o.w = 1.f/(1.f + __expf(-(a[r][3] + bg4.w)));
            *reinterpret_cast<float4*>(gateg + (size_t)(gr0+r)*256 + col) = o;
        }
    }

    // ---- block 0: wbp = g (.) Wb (layout [c][h]), s12 = {S1[h], S2[h]} ----
    if (blockIdx.x == 0) {
        for (int i = tid; i < 1024; i += 256) wbp[i] = lnbg[i >> 3] * Wb[i];
        if (tid < 64) {
            int h = tid & 7, chunk = tid >> 3;
            float acc1 = 0.f, acc2 = 0.f;
            #pragma unroll
            for (int j = 0; j < 16; ++j) {
                int c = chunk*16 + j;
                float wv = Wb[c*8 + h];
                acc1 = fmaf(lnbg[c], wv, acc1);
                acc2 = fmaf(lnbb[c], wv, acc2);
            }
            p1_s[tid] = acc1; p2_s[tid] = acc2;
        }
        __syncthreads();
        if (tid < 16) {
            int h = tid & 7;
            const float* p = (tid < 8) ? p1_s : p2_s;
            float acc = 0.f;
            #pragma unroll
            for (int j = 0; j < 8; ++j) acc += p[h + 8*j];
            s12[tid] = acc;
        }
    }
}

// ---------------- kernel 2: bias LN + @Wb — coalesced, 16 lanes per row ----
// grid 2048 x 256; block = (b, q, k-half of 256). Wave handles 4 rows/pass,
// 16 lanes per row, each lane owns 8 bias cols; Wb' coefs live in registers.
__global__ __launch_bounds__(256) void k_bh(
    const float* __restrict__ bias, const int* __restrict__ mask,
    const float* __restrict__ wbp, const float* __restrict__ s12,
    float* __restrict__ bh)
{
    const int tid = threadIdx.x;
    const int bid = blockIdx.x;
    const int b  = bid >> 10;
    const int q  = (bid >> 1) & 511;
    const int k0 = (bid & 1) << 8;
    if (mask[(b << 9) + q] == 0) return;     // block-uniform exit

    const int w    = tid >> 6;
    const int lane = tid & 63;
    const int rq   = lane >> 4;              // row within pass quad
    const int sg   = lane & 15;              // lane within row-group
    const int h    = ((sg & 1) << 2) + (sg & 2) + ((sg >> 2) & 1);  // owned head

    // per-lane coefficient registers: cols c = 4sg..4sg+3 and 64+4sg..+3
    const float4* wbp4 = reinterpret_cast<const float4*>(wbp);
    float4 cA0[4], cB0[4], cA1[4], cB1[4];
    #pragma unroll
    for (int j = 0; j < 4; ++j) {
        int c0 = 4*sg + j, c1 = 64 + 4*sg + j;
        cA0[j] = wbp4[c0*2]; cB0[j] = wbp4[c0*2 + 1];
        cA1[j] = wbp4[c1*2]; cB1[j] = wbp4[c1*2 + 1];
    }
    const float S1 = s12[h], S2 = s12[8 + h];
    const float4* brow = reinterpret_cast<const float4*>(
        bias + (size_t)((b << 9) + q) * 512 * 128);

    for (int p = 0; p < 16; ++p) {
        const int k = k0 + p*16 + w*4 + rq;
        if (mask[(b << 9) + k] == 0) continue;   // row-group-uniform skip

        const float4* bp = brow + (size_t)k * 32;
        float4 v0 = bp[sg];          // cols 4sg..4sg+3   (coalesced 1KB/instr)
        float4 v1 = bp[16 + sg];     // cols 64+4sg..+3

        float s  = v0.x+v0.y+v0.z+v0.w + v1.x+v1.y+v1.z+v1.w;
        float ss = v0.x*v0.x; ss = fmaf(v0.y,v0.y, ss); ss = fmaf(v0.z,v0.z, ss);
        ss = fmaf(v0.w,v0.w, ss); ss = fmaf(v1.x,v1.x, ss); ss = fmaf(v1.y,v1.y, ss);
        ss = fmaf(v1.z,v1.z, ss); ss = fmaf(v1.w,v1.w, ss);

        float4 dA = {0.f,0.f,0.f,0.f}, dB = {0.f,0.f,0.f,0.f};
        FMA4(dA, v0.x, cA0[0]); FMA4(dB, v0.x, cB0[0]);
        FMA4(dA, v0.y, cA0[1]); FMA4(dB, v0.y, cB0[1]);
        FMA4(dA, v0.z, cA0[2]); FMA4(dB, v0.z, cB0[2]);
        FMA4(dA, v0.w, cA0[3]); FMA4(dB, v0.w, cB0[3]);
        FMA4(dA, v1.x, cA1[0]); FMA4(dB, v1.x, cB1[0]);
        FMA4(dA, v1.y, cA1[1]); FMA4(dB, v1.y, cB1[1]);
        FMA4(dA, v1.z, cA1[2]); FMA4(dB, v1.z, cB1[2]);
        FMA4(dA, v1.w, cA1[3]); FMA4(dB, v1.w, cB1[3]);

        // split-ownership tree over 16 lanes: 8 head-dots -> 1 per lane (8 shfl)
        float4 give = (sg & 1) ? dA : dB;      // keep heads (sg&1)?4-7:0-3
        float4 keep = (sg & 1) ? dB : dA;
        keep.x += __shfl_xor(give.x, 1); keep.y += __shfl_xor(give.y, 1);
        keep.z += __shfl_xor(give.z, 1); keep.w += __shfl_xor(give.w, 1);
        float g0 = (sg & 2) ? keep.x : keep.z;
        float g1 = (sg & 2) ? keep.y : keep.w;
        float e0 = (sg & 2) ? keep.z : keep.x;
        float e1 = (sg & 2) ? keep.w : keep.y;
        e0 += __shfl_xor(g0, 2); e1 += __shfl_xor(g1, 2);
        float g2 = (sg & 4) ? e0 : e1;
        float dsum = (sg & 4) ? e1 : e0;
        dsum += __shfl_xor(g2, 4);
        dsum += __shfl_xor(dsum, 8);

        // s, ss all-reduce over 16 lanes (8 shfl)
        #pragma unroll
        for (int m = 1; m < 16; m <<= 1) {
            s  += __shfl_xor(s,  m);
            ss += __shfl_xor(ss, m);
        }
        float mean = s * (1.f/128.f);
        float rstd = rsqrtf(ss*(1.f/128.f) - mean*mean + 1e-5f);
        if (sg < 8)
            bh[((size_t)((b*8 + h) * 512) + q) * 512 + k] = rstd * (dsum - mean*S1) + S2;
    }
}

// ---------------- kernel 3: attention + gate + Wo + mask ----------------
// grid 256 x 1024; block = (b, 4-query tile); wave = (head, k-half).
// Each wave does 2 k-tiles of 128, then flash-combine via LDS.
__global__ __launch_bounds__(1024) void k_attn(
    const float* __restrict__ qg, const float* __restrict__ ktg,
    const float* __restrict__ vg, const float* __restrict__ gateg,
    const float* __restrict__ bh, const int* __restrict__ mask,
    const float* __restrict__ Wo, const float* __restrict__ bo,
    float* __restrict__ out)
{
    __shared__ float q_s[4][256];
    __shared__ float p_s[2][32][128];      // [half][h*4+q][k]
    __shared__ float acc_s[2][8][4][32];   // [half][h][q][d]
    __shared__ float m_sh[2][8][4];
    __shared__ float d_sh[2][8][4];
    __shared__ float gx_s[4][256];

    const int tid = threadIdx.x;
    const int bid = blockIdx.x;
    const int b  = bid >> 7;
    const int q0 = (bid & 127) << 2;
    const int wd = tid >> 6;
    const int h = wd & 7, half = wd >> 3;
    const int lane = tid & 63;
    const int ql = lane >> 5, dd2 = lane & 31;
    const int mq = b << 9;

    q_s[tid >> 8][tid & 255] = qg[(size_t)(mq + q0 + (tid >> 8)) * 256 + (tid & 255)];
    __syncthreads();

    float mrun[4] = {-1e30f, -1e30f, -1e30f, -1e30f};
    float sden[4] = {0.f, 0.f, 0.f, 0.f};
    float a0A=0.f, a0B=0.f, a1A=0.f, a1B=0.f;

    #pragma unroll
    for (int t = 0; t < 2; ++t) {
        const int k0 = (half*2 + t) << 7;
        const int mkA = (mask[mq + k0 + lane] == 0);
        const int mkB = (mask[mq + k0 + 64 + lane] == 0);

        float bhA[4], bhB[4];
        #pragma unroll
        for (int qq = 0; qq < 4; ++qq) {
            const float* r = bh + (((size_t)(b*8 + h) * 512) + q0 + qq) * 512 + k0;
            bhA[qq] = r[lane];
            bhB[qq] = r[64 + lane];
        }

        // QK^T: lanes hold 2 keys each
        float lA[4] = {0.f,0.f,0.f,0.f}, lB[4] = {0.f,0.f,0.f,0.f};
        const float* kbase = ktg + ((size_t)(b*8 + h) * 32) * 512 + k0 + lane;
        #pragma unroll
        for (int d4 = 0; d4 < 32; d4 += 4) {
            float4 q4[4];
            #pragma unroll
            for (int qq = 0; qq < 4; ++qq)
                q4[qq] = *reinterpret_cast<const float4*>(&q_s[qq][(h << 5) + d4]);
            float kv0[4], kv1[4];
            #pragma unroll
            for (int j = 0; j < 4; ++j) {
                kv0[j] = kbase[(d4 + j) * 512];
                kv1[j] = kbase[(d4 + j) * 512 + 64];
            }
            #pragma unroll
            for (int qq = 0; qq < 4; ++qq) {
                lA[qq] = fmaf(q4[qq].x, kv0[0], lA[qq]);
                lA[qq] = fmaf(q4[qq].y, kv0[1], lA[qq]);
                lA[qq] = fmaf(q4[qq].z, kv0[2], lA[qq]);
                lA[qq] = fmaf(q4[qq].w, kv0[3], lA[qq]);
                lB[qq] = fmaf(q4[qq].x, kv1[0], lB[qq]);
                lB[qq] = fmaf(q4[qq].y, kv1[1], lB[qq]);
                lB[qq] = fmaf(q4[qq].z, kv1[2], lB[qq]);
                lB[qq] = fmaf(q4[qq].w, kv1[3], lB[qq]);
            }
        }

        // online softmax (per-wave)
        float corr4[4];
        #pragma unroll
        for (int qq = 0; qq < 4; ++qq) {
            float la = mkA ? -1e30f : (lA[qq] + bhA[qq]);
            float lb = mkB ? -1e30f : (lB[qq] + bhB[qq]);
            float mx = fmaxf(la, lb);
            #pragma unroll
            for (int m = 1; m < 64; m <<= 1) mx = fmaxf(mx, __shfl_xor(mx, m));
            float mnew = fmaxf(mrun[qq], mx);
            float corr = __expf(mrun[qq] - mnew);
            float pa = mkA ? 0.f : __expf(la - mnew);
            float pb = mkB ? 0.f : __expf(lb - mnew);
            float ts = pa + pb;
            #pragma unroll
            for (int m = 1; m < 64; m <<= 1) ts += __shfl_xor(ts, m);
            sden[qq] = sden[qq] * corr + ts;
            mrun[qq] = mnew;
            corr4[qq] = corr;
            p_s[half][(h << 2) + qq][lane]      = pa;
            p_s[half][(h << 2) + qq][64 + lane] = pb;
        }

        // PV: lane = (q-pair, d); branch-free streaming FMA
        float c0 = ql ? corr4[1] : corr4[0];
        float c1 = ql ? corr4[3] : corr4[2];
        a0A *= c0; a0B *= c0; a1A *= c1; a1B *= c1;
        const float* vbase = vg + ((size_t)mq + k0) * 256 + (h << 5) + dd2;
        const float* pr0 = p_s[half][(h << 2) + ql];
        const float* pr1 = p_s[half][(h << 2) + ql + 2];
        #pragma unroll 4
        for (int k = 0; k < 128; k += 8) {
            float4 p0a = *reinterpret_cast<const float4*>(pr0 + k);
            float4 p0b = *reinterpret_cast<const float4*>(pr0 + k + 4);
            float4 p1a = *reinterpret_cast<const float4*>(pr1 + k);
            float4 p1b = *reinterpret_cast<const float4*>(pr1 + k + 4);
            float v0 = vbase[(k+0)*256], v1 = vbase[(k+1)*256];
            float v2 = vbase[(k+2)*256], v3 = vbase[(k+3)*256];
            float v4 = vbase[(k+4)*256], v5 = vbase[(k+5)*256];
            float v6 = vbase[(k+6)*256], v7 = vbase[(k+7)*256];
            a0A = fmaf(p0a.x,v0, fmaf(p0a.y,v1, fmaf(p0a.z,v2, fmaf(p0a.w,v3, a0A))));
            a0B = fmaf(p0b.x,v4, fmaf(p0b.y,v5, fmaf(p0b.z,v6, fmaf(p0b.w,v7, a0B))));
            a1A = fmaf(p1a.x,v0, fmaf(p1a.y,v1, fmaf(p1a.z,v2, fmaf(p1a.w,v3, a1A))));
            a1B = fmaf(p1b.x,v4, fmaf(p1b.y,v5, fmaf(p1b.z,v6, fmaf(p1b.w,v7, a1B))));
        }
    }

    // publish per-half state
    float a0 = a0A + a0B, a1 = a1A + a1B;
    acc_s[half][h][ql][dd2]     = a0;
    acc_s[half][h][ql + 2][dd2] = a1;
    if (lane == 0) {
        m_sh[half][h][0] = mrun[0]; m_sh[half][h][1] = mrun[1];
        m_sh[half][h][2] = mrun[2]; m_sh[half][h][3] = mrun[3];
        d_sh[half][h][0] = sden[0]; d_sh[half][h][1] = sden[1];
        d_sh[half][h][2] = sden[2]; d_sh[half][h][3] = sden[3];
    }
    __syncthreads();

    // flash-combine (half 0 waves merge half 1), normalize + gate
    if (half == 0) {
        float f0[4], f1[4], sm[4];
        #pragma unroll
        for (int qq = 0; qq < 4; ++qq) {
            float m1 = m_sh[1][h][qq];
            float s1 = d_sh[1][h][qq];
            float M  = fmaxf(mrun[qq], m1);
            f0[qq] = __expf(mrun[qq] - M);
            f1[qq] = __expf(m1 - M);
            sm[qq] = sden[qq] * f0[qq] + s1 * f1[qq];
        }
        float b0 = acc_s[1][h][ql][dd2];
        float b1 = acc_s[1][h][ql + 2][dd2];
        float f0a = ql ? f0[1] : f0[0], f1a = ql ? f1[1] : f1[0];
        float f0b = ql ? f0[3] : f0[2], f1b = ql ? f1[3] : f1[2];
        float sd0 = ql ? sm[1] : sm[0], sd1 = ql ? sm[3] : sm[2];
        float A0 = a0 * f0a + b0 * f1a;
        float A1 = a1 * f0b + b1 * f1b;
        float g0 = gateg[(size_t)(mq + q0 + ql) * 256 + (h << 5) + dd2];
        float g1 = gateg[(size_t)(mq + q0 + ql + 2) * 256 + (h << 5) + dd2];
        gx_s[ql][(h << 5) + dd2]     = A0 / sd0 * g0;
        gx_s[ql + 2][(h << 5) + dd2] = A1 / sd1 * g1;
    }
    __syncthreads();

    // @Wo + bo, mask-zero: 1024 threads, one (q,c) each
    const int r2 = tid >> 8, cc = tid & 255;
    const int iv = (mask[mq + q0 + r2] == 0);
    float o = bo[cc];
    #pragma unroll 8
    for (int c = 0; c < 256; c += 4) {
        float4 gA = *reinterpret_cast<const float4*>(&gx_s[r2][c]);
        float w0 = Wo[(size_t)(c+0)*256 + cc];
        float w1 = Wo[(size_t)(c+1)*256 + cc];
        float w2 = Wo[(size_t)(c+2)*256 + cc];
        float w3 = Wo[(size_t)(c+3)*256 + cc];
        o = fmaf(gA.w,w3, fmaf(gA.z,w2, fmaf(gA.y,w1, fmaf(gA.x,w0, o))));
    }
    out[(size_t)(mq + q0 + r2) * 256 + cc] = iv ? 0.f : o;
}

extern "C" void kernel_launch(void* const* d_in, const int* in_sizes, int n_in,
                              void* d_out, int out_size, void* d_ws, size_t ws_size,
                              hipStream_t stream)
{
    const float* x    = (const float*)d_in[0];
    const float* bias = (const float*)d_in[1];
    const int*   mask = (const int*)d_in[2];
    const float* lng  = (const float*)d_in[3];
    const float* lnb  = (const float*)d_in[4];
    const float* lnbg = (const float*)d_in[5];
    const float* lnbb = (const float*)d_in[6];
    const float* Wq   = (const float*)d_in[7];
    const float* Wk   = (const float*)d_in[8];
    const float* Wv   = (const float*)d_in[9];
    const float* Wb   = (const float*)d_in[10];
    const float* Wg   = (const float*)d_in[11];
    const float* bgv  = (const float*)d_in[12];
    const float* Wo   = (const float*)d_in[13];
    const float* bo   = (const float*)d_in[14];
    float* out = (float*)d_out;

    float* ws    = (float*)d_ws;
    float* qg    = ws;                    // 262144
    float* ktg   = qg    + 262144;        // 262144 (transposed [b][h][d][L])
    float* vg    = ktg   + 262144;        // 262144
    float* gateg = vg    + 262144;        // 262144
    float* bhg   = gateg + 262144;        // 4194304  [b][h][q][k]
    float* wbp   = bhg   + 4194304;       // 1024  (g .* Wb, [c][h])
    float* s12   = wbp   + 1024;          // 16    ({S1[h], S2[h]})

    hipLaunchKernelGGL(k1_proj, dim3(256), dim3(256), 0, stream,
        x, lng, lnb, Wq, Wk, Wv, Wg, bgv, lnbg, lnbb, Wb,
        qg, ktg, vg, gateg, wbp, s12);
    hipLaunchKernelGGL(k_bh, dim3(2048), dim3(256), 0, stream,
        bias, mask, wbp, s12, bhg);
    hipLaunchKernelGGL(k_attn, dim3(256), dim3(1024), 0, stream,
        qg, ktg, vg, gateg, bhg, mask, Wo, bo, out);
}